// Round 10
// baseline (409.599 us; speedup 1.0000x reference)
//
#include <hip/hip_runtime.h>
#include <hip/hip_bf16.h>
#include <stdint.h>

// ---------- types ----------
typedef __attribute__((ext_vector_type(8))) short     bf16x8;  // MFMA A/B frag (4 VGPR)
typedef __attribute__((ext_vector_type(4))) float     f32x4;   // MFMA C/D frag

__device__ __forceinline__ unsigned short f2bf(float f) {
  unsigned int u = __float_as_uint(f);
  u += 0x7FFFu + ((u >> 16) & 1u);   // round-to-nearest-even
  return (unsigned short)(u >> 16);
}

__device__ __forceinline__ void async_cp16(const void* g, void* l) {
  __builtin_amdgcn_global_load_lds((const __attribute__((address_space(1))) void*)g,
                                   (__attribute__((address_space(3))) void*)l,
                                   16, 0, 0);
}

// ---------- merged fp32 -> bf16 conversion (one launch for x, wug-perm, wd) --
// float4-unit ranges: x [0, 7340032), wug [7340032, 14680064), wd [.., 18350080)
// wug permute: out row r: g = r>>5, w = r&31; src = g*16 + (w&15) + (w&16?2048:0)
// -> each 32-row group = 16 gate rows + 16 up rows of the same e-block.
__global__ __launch_bounds__(256) void cvt_all(const float* __restrict__ x,
                                               const float* __restrict__ wug,
                                               const float* __restrict__ wd,
                                               unsigned short* __restrict__ xb,
                                               unsigned short* __restrict__ wub,
                                               unsigned short* __restrict__ wdb) {
  int i = blockIdx.x * blockDim.x + threadIdx.x;
  const int stride = gridDim.x * blockDim.x;
  for (; i < 18350080; i += stride) {
    float4 v; ushort4* dp;
    if (i < 7340032) {
      v = ((const float4*)x)[i];
      dp = (ushort4*)xb + i;
    } else if (i < 14680064) {
      const int k = i - 7340032;
      const int r = k / 1792, c = k - r * 1792;
      const int g = r >> 5, w = r & 31;
      const int src = g * 16 + (w & 15) + ((w & 16) ? 2048 : 0);
      v = ((const float4*)wug)[(size_t)src * 1792 + c];
      dp = (ushort4*)wub + k;
    } else {
      const int k = i - 14680064;
      v = ((const float4*)wd)[k];
      dp = (ushort4*)wdb + k;
    }
    ushort4 o;
    o.x = f2bf(v.x); o.y = f2bf(v.y); o.z = f2bf(v.z); o.w = f2bf(v.w);
    *dp = o;
  }
}

// ---------- 256x256 reg-pipelined NT bf16 GEMM (round-3 ring + frag pipeline)
// C[m,n] = sum_k A[m,k]*B[n,k].  512 thr = 8 waves (2Mx4N), wave-tile 128x64.
// LDS ring-4 at kstep (BK=32) granularity: slot = 16K A + 16K B, 128 KiB.
// REGISTER PIPELINE: frags(h)'s Q0 set (A mh0 + all B) is read during kstep
// h-1, so at the barrier exit kstep h's first 16-MFMA cluster issues with ZERO
// LDS dependency. The 12 ds_reads for {a1(h), frags(h+1)} then issue UNDER the
// Q0 cluster's ~620 cyc/SIMD drain (MFMA issue != drain; barriers don't wait
// for the matrix pipe) -> LDS traffic comes off the matrix critical path.
// This was rounds 3/9's missing overlap: measured 4431 cyc/K-tile = 2484
// (matrix demand) + ~1950 (LDS demand) = serial sum.
// Per kstep: MFMA Q0 (16) | read a1 (4) + frags(h+1) (8) | STAGE(h+3, 4 loads)
// | MFMA Q1 (16) | vmcnt(4) | barrier.  Counted vmcnt, never 0.
// Ring-4 invariants (proven rounds 2-3-9): stage target slot (h+3)&3 last read
// kstep h-1 (barrier-separated); vmcnt(4) at h end drains stage(h+2) -> slot
// h+2 resident for kstep h+1's pre-reads of frags(h+2).
// __launch_bounds__(512,1): 256 VGPRs (round-8's identical structure died from
// the (512,2) 128-VGPR cap -> spill storm; LDS=128K gives 1 block/CU anyway).
// Swizzle (0-conflict, verified): line L (128B) = rows 2L,2L+1; 16B phys slot
// p holds logical q = p ^ (L&7); staging pre-swizzles the per-lane GLOBAL
// source, LDS dest stays linear (m173).
// FUSE_SWIGLU: B rows pre-permuted so acc n in {0,2}=gate, {1,3}=up of the
// same e-cols -> h = silu(g)*u in-lane, write [M, N/2] bf16.
template <int K, int N, bool FUSE_SWIGLU>
__global__ __launch_bounds__(512, 1) void gemm_nt(const unsigned short* __restrict__ A,
                                                  const unsigned short* __restrict__ B,
                                                  void* __restrict__ Cv) {
  extern __shared__ char sm[];   // 131072 bytes: [4 slots x 16KB A][4 slots x 16KB B]
  constexpr int nbx = N / 256;
  constexpr int nwg = (4096 / 256) * nbx;
  constexpr size_t K2 = (size_t)K * 2;
  constexpr int nh = K / 32;     // ksteps (even for both GEMMs)

  // T1: bijective XCD swizzle (nwg % 8 == 0 for both GEMMs)
  const int bid = blockIdx.x;
  constexpr int q8 = nwg / 8;
  const int swz = (bid & 7) * q8 + (bid >> 3);
  const int bx = swz % nbx, by = swz / nbx;
  const int row0 = by * 256, col0 = bx * 256;

  const int tid = threadIdx.x, wave = tid >> 6, lane = tid & 63;
  const int wr = wave >> 2, wc = wave & 3;       // wave 2x4 grid
  const int fr = lane & 15, fg = lane >> 4;      // fragment row / k-group

  // ---- staging addresses (pre-swizzled global source, linear LDS dest) ----
  const int l3 = lane >> 3;                 // 0..7
  const int q  = (lane & 7) ^ l3;           // 0..7 involution
  const int qr = q >> 2;                    // row parity
  const int qc = (q & 3) * 16;              // byte offset within kstep's 64B row
  const char* gA[2]; const char* gB[2];
#pragma unroll
  for (int i = 0; i < 2; ++i) {
    const int L = i * 64 + wave * 8 + l3;   // LDS line 0..127
    gA[i] = (const char*)A + (size_t)(row0 + 2 * L + qr) * K2 + qc;
    gB[i] = (const char*)B + (size_t)(col0 + 2 * L + qr) * K2 + qc;
  }

  // ---- fragment read offsets (swizzled) ----
  const int rbA = wr * 128 + fr;
  const int offA0 = (rbA >> 1) * 128 + (((((rbA & 1) << 2) | fg) ^ ((rbA >> 1) & 7)) << 4);
  const int rbB = wc * 64 + fr;
  const int offB0 = (rbB >> 1) * 128 + (((((rbB & 1) << 2) | fg) ^ ((rbB >> 1) & 7)) << 4);

  f32x4 acc[8][4];
#pragma unroll
  for (int m = 0; m < 8; ++m)
#pragma unroll
    for (int n = 0; n < 4; ++n) acc[m][n] = (f32x4){0.f, 0.f, 0.f, 0.f};

#define STAGE(h, slot) do {                                     \
    char* dA_ = sm + (slot) * 16384 + wave * 1024;              \
    char* dB_ = sm + 65536 + (slot) * 16384 + wave * 1024;      \
    async_cp16(gA[0] + (size_t)(h) * 64, dA_);                  \
    async_cp16(gA[1] + (size_t)(h) * 64, dA_ + 8192);           \
    async_cp16(gB[0] + (size_t)(h) * 64, dB_);                  \
    async_cp16(gB[1] + (size_t)(h) * 64, dB_ + 8192);           \
  } while (0)

  // KSTEP(hh): Q0-frags(hh) pre-read in {AP0,BP}; reads next set into {AQ0,BQ}.
#define KSTEP(hh, AP0, BP, AQ0, BQ) do {                                    \
    const int hs_ = ((hh) + 3 < nh) ? (hh) + 3 : nh - 1;                    \
    const int ss_ = ((hh) + 3) & 3;                                         \
    const char* aC_ = sm + ((hh) & 3) * 16384;                              \
    const char* aN_ = sm + (((hh) + 1) & 3) * 16384;                        \
    const char* bN_ = sm + 65536 + (((hh) + 1) & 3) * 16384;                \
    __builtin_amdgcn_s_setprio(1);                                          \
    _Pragma("unroll") for (int m_ = 0; m_ < 4; ++m_)                        \
      _Pragma("unroll") for (int n_ = 0; n_ < 4; ++n_)                      \
        acc[m_][n_] = __builtin_amdgcn_mfma_f32_16x16x32_bf16(              \
            AP0[m_], BP[n_], acc[m_][n_], 0, 0, 0);                         \
    __builtin_amdgcn_s_setprio(0);                                          \
    bf16x8 a1_[4];                                                          \
    _Pragma("unroll") for (int m_ = 0; m_ < 4; ++m_)                        \
      a1_[m_] = *(const bf16x8*)(aC_ + offA0 + (m_ + 4) * 1024);            \
    if ((hh) + 1 < nh) {                                                    \
      _Pragma("unroll") for (int n_ = 0; n_ < 4; ++n_)                      \
        BQ[n_] = *(const bf16x8*)(bN_ + offB0 + n_ * 1024);                 \
      _Pragma("unroll") for (int m_ = 0; m_ < 4; ++m_)                      \
        AQ0[m_] = *(const bf16x8*)(aN_ + offA0 + m_ * 1024);                \
    }                                                                       \
    STAGE(hs_, ss_);                                                        \
    __builtin_amdgcn_s_setprio(1);                                          \
    _Pragma("unroll") for (int m_ = 0; m_ < 4; ++m_)                        \
      _Pragma("unroll") for (int n_ = 0; n_ < 4; ++n_)                      \
        acc[m_ + 4][n_] = __builtin_amdgcn_mfma_f32_16x16x32_bf16(          \
            a1_[m_], BP[n_], acc[m_ + 4][n_], 0, 0, 0);                     \
    __builtin_amdgcn_s_setprio(0);                                          \
    asm volatile("s_waitcnt vmcnt(4)" ::: "memory");                        \
    __builtin_amdgcn_s_barrier();                                           \
  } while (0)

  // prologue: stage ksteps 0,1,2 (12 loads); vmcnt(4) -> slots 0,1 resident;
  // pre-read kstep 0's Q0 set.
  STAGE(0, 0); STAGE(1, 1); STAGE(2, 2);
  asm volatile("s_waitcnt vmcnt(4)" ::: "memory");
  __builtin_amdgcn_s_barrier();

  bf16x8 aP0[4], bP[4], aQ0[4], bQ[4];
#pragma unroll
  for (int n = 0; n < 4; ++n) bP[n] = *(const bf16x8*)(sm + 65536 + offB0 + n * 1024);
#pragma unroll
  for (int m = 0; m < 4; ++m) aP0[m] = *(const bf16x8*)(sm + offA0 + m * 1024);

  // invariant at kstep h top: Q0-frags(h) in regs; slots h, h+1 resident;
  // stage(h+2) in flight (4 loads).
  for (int h = 0; h < nh; h += 2) {
    KSTEP(h,     aP0, bP, aQ0, bQ);
    KSTEP(h + 1, aQ0, bQ, aP0, bP);
  }
#undef STAGE
#undef KSTEP

  // ---- epilogue: C/D layout col = lane&15, row = (lane>>4)*4 + j (m89-verified) ----
  const int rowb = row0 + wr * 128 + fg * 4;
  if (FUSE_SWIGLU) {
    // acc n in {0,2}: gate; {1,3}: up, same e-cols (pre-permuted B)
    unsigned short* Hp = (unsigned short*)Cv;
    const int ecb = ((col0 + wc * 64) >> 1) + fr;
#pragma unroll
    for (int m = 0; m < 8; ++m)
#pragma unroll
      for (int p = 0; p < 2; ++p)
#pragma unroll
        for (int j = 0; j < 4; ++j) {
          const float gv = acc[m][2 * p][j];
          const float uv = acc[m][2 * p + 1][j];
          const float s  = gv / (1.0f + __expf(-gv));
          Hp[(size_t)(rowb + m * 16 + j) * (N / 2) + (ecb + p * 16)] = f2bf(s * uv);
        }
  } else {
    float* Cp = (float*)Cv;
    const int colb = col0 + wc * 64 + fr;
#pragma unroll
    for (int m = 0; m < 8; ++m)
#pragma unroll
      for (int n = 0; n < 4; ++n)
#pragma unroll
        for (int j = 0; j < 4; ++j)
          Cp[(size_t)(rowb + m * 16 + j) * N + (colb + n * 16)] = acc[m][n][j];
  }
}

// ---------- launch ----------
extern "C" void kernel_launch(void* const* d_in, const int* in_sizes, int n_in,
                              void* d_out, int out_size, void* d_ws, size_t ws_size,
                              hipStream_t stream) {
  const int M = 4096, K = 7168, E = 2048;

  const float* x   = (const float*)d_in[0];  // [M,K]
  const float* wug = (const float*)d_in[1];  // [2E,K]
  const float* wd  = (const float*)d_in[2];  // [K,E]
  float* out = (float*)d_out;                // [M,K]

  // workspace layout (bytes)
  char* ws = (char*)d_ws;
  unsigned short* xb  = (unsigned short*)(ws);               //  58,720,256
  unsigned short* wub = (unsigned short*)(ws + 58720256);    //  58,720,256 (permuted)
  unsigned short* wdb = (unsigned short*)(ws + 117440512);   //  29,360,128
  unsigned short* h   = (unsigned short*)(ws + 146800640);   //  16,777,216
  if (ws_size < 163577856) return;                           // need ~156 MiB

  // allow 128 KiB dynamic LDS (host-side calls, safe under graph capture)
  hipFuncSetAttribute((const void*)gemm_nt<7168, 4096, true>,
                      hipFuncAttributeMaxDynamicSharedMemorySize, 131072);
  hipFuncSetAttribute((const void*)gemm_nt<2048, 7168, false>,
                      hipFuncAttributeMaxDynamicSharedMemorySize, 131072);

  // 1) cast inputs to bf16 (single merged launch; wug with gate/up permutation)
  cvt_all<<<2048, 256, 0, stream>>>(x, wug, wd, xb, wub, wdb);

  // 2) h = swiglu(x @ w_up_gate^T) fused   [4096, 2048] bf16  (16x16 = 256 blocks)
  gemm_nt<7168, 4096, true><<<256, 512, 131072, stream>>>(xb, wub, h);

  // 3) out = h @ w_down^T     [4096, 7168] fp32  (16x28 = 448 blocks)
  gemm_nt<2048, 7168, false><<<448, 512, 131072, stream>>>(h, wdb, out);
}

// Round 11
// 404.604 us; speedup vs baseline: 1.0123x; 1.0123x over previous
//
#include <hip/hip_runtime.h>
#include <hip/hip_bf16.h>
#include <stdint.h>

// ---------- types ----------
typedef __attribute__((ext_vector_type(8))) short     bf16x8;  // MFMA A/B frag (4 VGPR)
typedef __attribute__((ext_vector_type(4))) float     f32x4;   // MFMA C/D frag

__device__ __forceinline__ unsigned short f2bf(float f) {
  unsigned int u = __float_as_uint(f);
  u += 0x7FFFu + ((u >> 16) & 1u);   // round-to-nearest-even
  return (unsigned short)(u >> 16);
}

__device__ __forceinline__ void async_cp16(const void* g, void* l) {
  __builtin_amdgcn_global_load_lds((const __attribute__((address_space(1))) void*)g,
                                   (__attribute__((address_space(3))) void*)l,
                                   16, 0, 0);
}

// ---------- merged fp32 -> bf16 conversion (one launch for x, wug-perm, wd) --
// float4-unit ranges: x [0, 7340032), wug [7340032, 14680064), wd [.., 18350080)
// wug permute: out row r: g = r>>5, w = r&31; src = g*16 + (w&15) + (w&16?2048:0)
// -> each 32-row group = 16 gate rows + 16 up rows of the same e-block.
__global__ __launch_bounds__(256) void cvt_all(const float* __restrict__ x,
                                               const float* __restrict__ wug,
                                               const float* __restrict__ wd,
                                               unsigned short* __restrict__ xb,
                                               unsigned short* __restrict__ wub,
                                               unsigned short* __restrict__ wdb) {
  int i = blockIdx.x * blockDim.x + threadIdx.x;
  const int stride = gridDim.x * blockDim.x;
  for (; i < 18350080; i += stride) {
    float4 v; ushort4* dp;
    if (i < 7340032) {
      v = ((const float4*)x)[i];
      dp = (ushort4*)xb + i;
    } else if (i < 14680064) {
      const int k = i - 7340032;
      const int r = k / 1792, c = k - r * 1792;
      const int g = r >> 5, w = r & 31;
      const int src = g * 16 + (w & 15) + ((w & 16) ? 2048 : 0);
      v = ((const float4*)wug)[(size_t)src * 1792 + c];
      dp = (ushort4*)wub + k;
    } else {
      const int k = i - 14680064;
      v = ((const float4*)wd)[k];
      dp = (ushort4*)wdb + k;
    }
    ushort4 o;
    o.x = f2bf(v.x); o.y = f2bf(v.y); o.z = f2bf(v.z); o.w = f2bf(v.w);
    *dp = o;
  }
}

// ---------- 256x256 reg-pipelined NT bf16 GEMM with PINNED schedule ---------
// C[m,n] = sum_k A[m,k]*B[n,k].  512 thr = 8 waves (2Mx4N), wave-tile 128x64.
// LDS ring-4 at kstep (BK=32) granularity: slot = 16K A + 16K B, 128 KiB.
// Round-10 structure + sched_barrier(0) pins. Round-10's VGPR_Count=116 proved
// the compiler COLLAPSED the register pipeline (sank the h+1 pre-reads down to
// just-before-use -> reads back on the matrix critical path). The pins force:
//   [MFMA Q0: 16, zero LDS dep]  <- issues immediately at barrier exit
//   SBAR(0)
//   [12 ds_reads: a1(h) + Q0-frags(h+1) | STAGE(h+3): 4 gloads]
//   SBAR(0)                      <- reads pinned ABOVE Q1, issue under Q0 drain
//   [MFMA Q1: 16 (a1 x bP)]
//   vmcnt(4)  barrier            <- counted: drains stage(h+2), leaves h+3
// Ring-4 invariants (proven rounds 2/3/9/10): stage target slot (h+3)&3 last
// read kstep h-1 (barrier-separated); vmcnt(4) at h end makes slot h+2
// resident for kstep h+1's pre-reads of frags(h+2); tile-(h+1) reads during h
// were staged at h-2 and vmcnt'd+barrier'd at end of h-1 (cross-wave safe).
// __launch_bounds__(512,1): 256 VGPR cap; true pipeline needs ~240-250.
// Swizzle (0-conflict, verified): line L (128B) = rows 2L,2L+1; 16B phys slot
// p holds logical q = p ^ (L&7); staging pre-swizzles the per-lane GLOBAL
// source, LDS dest stays linear (m173).
// FUSE_SWIGLU: B rows pre-permuted so acc n in {0,2}=gate, {1,3}=up of the
// same e-cols -> h = silu(g)*u in-lane, write [M, N/2] bf16.
template <int K, int N, bool FUSE_SWIGLU>
__global__ __launch_bounds__(512, 1) void gemm_nt(const unsigned short* __restrict__ A,
                                                  const unsigned short* __restrict__ B,
                                                  void* __restrict__ Cv) {
  extern __shared__ char sm[];   // 131072 bytes: [4 slots x 16KB A][4 slots x 16KB B]
  constexpr int nbx = N / 256;
  constexpr int nwg = (4096 / 256) * nbx;
  constexpr size_t K2 = (size_t)K * 2;
  constexpr int nh = K / 32;     // ksteps (even for both GEMMs)

  // T1: bijective XCD swizzle (nwg % 8 == 0 for both GEMMs)
  const int bid = blockIdx.x;
  constexpr int q8 = nwg / 8;
  const int swz = (bid & 7) * q8 + (bid >> 3);
  const int bx = swz % nbx, by = swz / nbx;
  const int row0 = by * 256, col0 = bx * 256;

  const int tid = threadIdx.x, wave = tid >> 6, lane = tid & 63;
  const int wr = wave >> 2, wc = wave & 3;       // wave 2x4 grid
  const int fr = lane & 15, fg = lane >> 4;      // fragment row / k-group

  // ---- staging addresses (pre-swizzled global source, linear LDS dest) ----
  const int l3 = lane >> 3;                 // 0..7
  const int q  = (lane & 7) ^ l3;           // 0..7 involution
  const int qr = q >> 2;                    // row parity
  const int qc = (q & 3) * 16;              // byte offset within kstep's 64B row
  const char* gA[2]; const char* gB[2];
#pragma unroll
  for (int i = 0; i < 2; ++i) {
    const int L = i * 64 + wave * 8 + l3;   // LDS line 0..127
    gA[i] = (const char*)A + (size_t)(row0 + 2 * L + qr) * K2 + qc;
    gB[i] = (const char*)B + (size_t)(col0 + 2 * L + qr) * K2 + qc;
  }

  // ---- fragment read offsets (swizzled) ----
  const int rbA = wr * 128 + fr;
  const int offA0 = (rbA >> 1) * 128 + (((((rbA & 1) << 2) | fg) ^ ((rbA >> 1) & 7)) << 4);
  const int rbB = wc * 64 + fr;
  const int offB0 = (rbB >> 1) * 128 + (((((rbB & 1) << 2) | fg) ^ ((rbB >> 1) & 7)) << 4);

  f32x4 acc[8][4];
#pragma unroll
  for (int m = 0; m < 8; ++m)
#pragma unroll
    for (int n = 0; n < 4; ++n) acc[m][n] = (f32x4){0.f, 0.f, 0.f, 0.f};

#define STAGE(h, slot) do {                                     \
    char* dA_ = sm + (slot) * 16384 + wave * 1024;              \
    char* dB_ = sm + 65536 + (slot) * 16384 + wave * 1024;      \
    async_cp16(gA[0] + (size_t)(h) * 64, dA_);                  \
    async_cp16(gA[1] + (size_t)(h) * 64, dA_ + 8192);           \
    async_cp16(gB[0] + (size_t)(h) * 64, dB_);                  \
    async_cp16(gB[1] + (size_t)(h) * 64, dB_ + 8192);           \
  } while (0)

  // KSTEP(hh): Q0-frags(hh) pre-read in {AP0,BP}; pre-reads next into {AQ0,BQ}.
  // sched_barrier(0) pins: Q0 MFMAs FIRST, then reads+stage, then Q1 MFMAs.
#define KSTEP(hh, AP0, BP, AQ0, BQ) do {                                    \
    const int hs_ = ((hh) + 3 < nh) ? (hh) + 3 : nh - 1;                    \
    const int ss_ = ((hh) + 3) & 3;                                         \
    const char* aC_ = sm + ((hh) & 3) * 16384;                              \
    const char* aN_ = sm + (((hh) + 1) & 3) * 16384;                        \
    const char* bN_ = sm + 65536 + (((hh) + 1) & 3) * 16384;                \
    __builtin_amdgcn_s_setprio(1);                                          \
    _Pragma("unroll") for (int m_ = 0; m_ < 4; ++m_)                        \
      _Pragma("unroll") for (int n_ = 0; n_ < 4; ++n_)                      \
        acc[m_][n_] = __builtin_amdgcn_mfma_f32_16x16x32_bf16(              \
            AP0[m_], BP[n_], acc[m_][n_], 0, 0, 0);                         \
    __builtin_amdgcn_s_setprio(0);                                          \
    __builtin_amdgcn_sched_barrier(0);   /* pin: reads stay BELOW Q0 */     \
    bf16x8 a1_[4];                                                          \
    _Pragma("unroll") for (int m_ = 0; m_ < 4; ++m_)                        \
      a1_[m_] = *(const bf16x8*)(aC_ + offA0 + (m_ + 4) * 1024);            \
    if ((hh) + 1 < nh) {                                                    \
      _Pragma("unroll") for (int n_ = 0; n_ < 4; ++n_)                      \
        BQ[n_] = *(const bf16x8*)(bN_ + offB0 + n_ * 1024);                 \
      _Pragma("unroll") for (int m_ = 0; m_ < 4; ++m_)                      \
        AQ0[m_] = *(const bf16x8*)(aN_ + offA0 + m_ * 1024);                \
    }                                                                       \
    STAGE(hs_, ss_);                                                        \
    __builtin_amdgcn_sched_barrier(0);   /* pin: reads stay ABOVE Q1 */     \
    __builtin_amdgcn_s_setprio(1);                                          \
    _Pragma("unroll") for (int m_ = 0; m_ < 4; ++m_)                        \
      _Pragma("unroll") for (int n_ = 0; n_ < 4; ++n_)                      \
        acc[m_ + 4][n_] = __builtin_amdgcn_mfma_f32_16x16x32_bf16(          \
            a1_[m_], BP[n_], acc[m_ + 4][n_], 0, 0, 0);                     \
    __builtin_amdgcn_s_setprio(0);                                          \
    asm volatile("s_waitcnt vmcnt(4)" ::: "memory");                        \
    __builtin_amdgcn_s_barrier();                                           \
  } while (0)

  // prologue: stage ksteps 0,1,2 (12 loads); vmcnt(4) -> slots 0,1 resident;
  // pre-read kstep 0's Q0 set.
  STAGE(0, 0); STAGE(1, 1); STAGE(2, 2);
  asm volatile("s_waitcnt vmcnt(4)" ::: "memory");
  __builtin_amdgcn_s_barrier();

  bf16x8 aP0[4], bP[4], aQ0[4], bQ[4];
#pragma unroll
  for (int n = 0; n < 4; ++n) bP[n] = *(const bf16x8*)(sm + 65536 + offB0 + n * 1024);
#pragma unroll
  for (int m = 0; m < 4; ++m) aP0[m] = *(const bf16x8*)(sm + offA0 + m * 1024);

  // invariant at kstep h top: Q0-frags(h) in regs; slots h, h+1 resident;
  // stage(h+2) in flight (4 loads).
  for (int h = 0; h < nh; h += 2) {
    KSTEP(h,     aP0, bP, aQ0, bQ);
    KSTEP(h + 1, aQ0, bQ, aP0, bP);
  }
#undef STAGE
#undef KSTEP

  // ---- epilogue: C/D layout col = lane&15, row = (lane>>4)*4 + j (m89-verified) ----
  const int rowb = row0 + wr * 128 + fg * 4;
  if (FUSE_SWIGLU) {
    // acc n in {0,2}: gate; {1,3}: up, same e-cols (pre-permuted B)
    unsigned short* Hp = (unsigned short*)Cv;
    const int ecb = ((col0 + wc * 64) >> 1) + fr;
#pragma unroll
    for (int m = 0; m < 8; ++m)
#pragma unroll
      for (int p = 0; p < 2; ++p)
#pragma unroll
        for (int j = 0; j < 4; ++j) {
          const float gv = acc[m][2 * p][j];
          const float uv = acc[m][2 * p + 1][j];
          const float s  = gv / (1.0f + __expf(-gv));
          Hp[(size_t)(rowb + m * 16 + j) * (N / 2) + (ecb + p * 16)] = f2bf(s * uv);
        }
  } else {
    float* Cp = (float*)Cv;
    const int colb = col0 + wc * 64 + fr;
#pragma unroll
    for (int m = 0; m < 8; ++m)
#pragma unroll
      for (int n = 0; n < 4; ++n)
#pragma unroll
        for (int j = 0; j < 4; ++j)
          Cp[(size_t)(rowb + m * 16 + j) * N + (colb + n * 16)] = acc[m][n][j];
  }
}

// ---------- launch ----------
extern "C" void kernel_launch(void* const* d_in, const int* in_sizes, int n_in,
                              void* d_out, int out_size, void* d_ws, size_t ws_size,
                              hipStream_t stream) {
  const int M = 4096, K = 7168, E = 2048;

  const float* x   = (const float*)d_in[0];  // [M,K]
  const float* wug = (const float*)d_in[1];  // [2E,K]
  const float* wd  = (const float*)d_in[2];  // [K,E]
  float* out = (float*)d_out;                // [M,K]

  // workspace layout (bytes)
  char* ws = (char*)d_ws;
  unsigned short* xb  = (unsigned short*)(ws);               //  58,720,256
  unsigned short* wub = (unsigned short*)(ws + 58720256);    //  58,720,256 (permuted)
  unsigned short* wdb = (unsigned short*)(ws + 117440512);   //  29,360,128
  unsigned short* h   = (unsigned short*)(ws + 146800640);   //  16,777,216
  if (ws_size < 163577856) return;                           // need ~156 MiB

  // allow 128 KiB dynamic LDS (host-side calls, safe under graph capture)
  hipFuncSetAttribute((const void*)gemm_nt<7168, 4096, true>,
                      hipFuncAttributeMaxDynamicSharedMemorySize, 131072);
  hipFuncSetAttribute((const void*)gemm_nt<2048, 7168, false>,
                      hipFuncAttributeMaxDynamicSharedMemorySize, 131072);

  // 1) cast inputs to bf16 (single merged launch; wug with gate/up permutation)
  cvt_all<<<2048, 256, 0, stream>>>(x, wug, wd, xb, wub, wdb);

  // 2) h = swiglu(x @ w_up_gate^T) fused   [4096, 2048] bf16  (16x16 = 256 blocks)
  gemm_nt<7168, 4096, true><<<256, 512, 131072, stream>>>(xb, wub, h);

  // 3) out = h @ w_down^T     [4096, 7168] fp32  (16x28 = 448 blocks)
  gemm_nt<2048, 7168, false><<<448, 512, 131072, stream>>>(h, wdb, out);
}